// Round 1
// 373.998 us; speedup vs baseline: 1.0394x; 1.0394x over previous
//
#include <hip/hip_runtime.h>
#include <hip/hip_bf16.h>

#define NN 100000   // nodes
#define NE 1600000  // edges
#define FD 128      // IN_DIM = H*D
#define CD 112      // CONTENT_DIM
#define PDIM 16     // POS_DIM
#define NH 4        // heads
#define NB_SCAN 391 // ceil(NN/256)
#define NSHARD 8    // dst shards (one per XCD)
#define SHARD 12500 // NN / NSHARD
#define NE4 400000  // NE / 4
#define NB_E4 1563  // ceil(NE4 / 256)

#define NOUT 144        // 128 hc cols + 4 A + 4 B + 8 pad
#define MBLK 64         // nodes per block in node GEMM
#define LDS_STRIDE 136  // ushort stride per LDS row
#define WT_U (MBLK * LDS_STRIDE)
#define NGB 1563        // ceil(NN / MBLK)

using bf16x8 = __attribute__((ext_vector_type(8))) short;
using f32x4  = __attribute__((ext_vector_type(4))) float;

__device__ __forceinline__ unsigned short f2bf(float x) {
    union { float f; unsigned int u; } v; v.f = x;
    return (unsigned short)((v.u + 0x7fffu + ((v.u >> 16) & 1u)) >> 16);  // RNE
}
__device__ __forceinline__ float bf_lo(unsigned int u) { return __uint_as_float(u << 16); }
__device__ __forceinline__ float bf_hi(unsigned int u) { return __uint_as_float(u & 0xffff0000u); }

// ---------------- K0: build combined bf16 weight matrix W'T [144][128] ----
__global__ __launch_bounds__(256) void prep_kernel(
    const float* __restrict__ Wc, const float* __restrict__ Wp,
    const float* __restrict__ attn_src, const float* __restrict__ attn_dst,
    const float* __restrict__ pos_attn_src, const float* __restrict__ pos_attn_dst,
    const float* __restrict__ att_comb, unsigned short* __restrict__ wt)
{
    __shared__ float sA[NH * FD], sB[NH * FD];
    const int t = threadIdx.x;
    #pragma unroll
    for (int r = 0; r < 2; ++r) {
        const int idx = t + r * 256;       // 0..511
        const int h = idx >> 7, k = idx & 127;
        const float c0 = att_comb[h * 2], c1 = att_comb[h * 2 + 1];
        float sa = 0.f, sb = 0.f;
        if (k < CD) {
            #pragma unroll 8
            for (int d = 0; d < 32; ++d) {
                const float wv = Wc[(size_t)(h * 32 + d) * CD + k];
                sa = fmaf(wv, attn_src[h * 32 + d], sa);
                sb = fmaf(wv, attn_dst[h * 32 + d], sb);
            }
            sa *= c0; sb *= c0;
        } else {
            const int k2 = k - CD;
            #pragma unroll
            for (int d4 = 0; d4 < 8; ++d4) {
                const float wv = Wp[(h * 8 + d4) * PDIM + k2];
                sa = fmaf(wv, pos_attn_src[h * 8 + d4], sa);
                sb = fmaf(wv, pos_attn_dst[h * 8 + d4], sb);
            }
            sa *= c1; sb *= c1;
        }
        sA[idx] = sa; sB[idx] = sb;
    }
    __syncthreads();
    #pragma unroll
    for (int it = 0; it < 72; ++it) {
        const int e = t + it * 256;        // < 18432 = 144*128
        const int row = e >> 7, k = e & 127;
        float val;
        if (row < 128)      val = (k < CD) ? Wc[(size_t)row * CD + k] : 0.f;
        else if (row < 132) val = sA[(row - 128) * FD + k];
        else if (row < 136) val = sB[(row - 132) * FD + k];
        else                val = 0.f;
        wt[e] = f2bf(val);
    }
}

// ---------------- K1: degree histogram (XCD-sharded, int4) ----------------
__global__ __launch_bounds__(256) void hist_kernel(const int* __restrict__ dst,
                                                   int* __restrict__ deg) {
    const int shard = blockIdx.x & (NSHARD - 1);
    const int i4 = (blockIdx.x >> 3) * 256 + threadIdx.x;
    if (i4 >= NE4) return;
    const int4 d4 = ((const int4*)dst)[i4];
    const int lo = shard * SHARD, hi = lo + SHARD;
    if (d4.x >= lo && d4.x < hi) atomicAdd(&deg[d4.x], 1);
    if (d4.y >= lo && d4.y < hi) atomicAdd(&deg[d4.y], 1);
    if (d4.z >= lo && d4.z < hi) atomicAdd(&deg[d4.z], 1);
    if (d4.w >= lo && d4.w < hi) atomicAdd(&deg[d4.w], 1);
}

// ---------------- K2: node projections via MFMA ----------------
__global__ __launch_bounds__(256) void node_mfma_kernel(
    const float* __restrict__ feat, const unsigned short* __restrict__ wt,
    unsigned short* __restrict__ hc_bf, float* __restrict__ A,
    float* __restrict__ B)
{
    __shared__ __align__(16) unsigned short sm[WT_U + NOUT * LDS_STRIDE];  // 56,576 B
    unsigned int* smu = (unsigned int*)sm;
    const int t = threadIdx.x;
    const int n0 = blockIdx.x * MBLK;

    // feat staging: 64 rows x 128 f32 = 2048 float4, 8 iters
    #pragma unroll
    for (int it = 0; it < 8; ++it) {
        const int e4 = t + it * 256;           // float4 index < 2048
        const int row = e4 >> 5, c4 = e4 & 31;
        uint2 packed = make_uint2(0u, 0u);
        if (n0 + row < NN) {
            const float4 g = ((const float4*)(feat + (size_t)n0 * FD))[e4];
            packed.x = (unsigned int)f2bf(g.x) | ((unsigned int)f2bf(g.y) << 16);
            packed.y = (unsigned int)f2bf(g.z) | ((unsigned int)f2bf(g.w) << 16);
        }
        *(uint2*)&smu[row * (LDS_STRIDE / 2) + c4 * 2] = packed;
    }
    // wt staging: 144 rows x 64 u32 = 2304 uint4, 9 iters
    const uint4* wtu4 = (const uint4*)wt;
    #pragma unroll
    for (int it = 0; it < 9; ++it) {
        const int u4 = t + it * 256;           // uint4 index < 2304
        const int row = u4 >> 4, c16 = u4 & 15;
        *(uint4*)&smu[WT_U / 2 + row * (LDS_STRIDE / 2) + c16 * 4] = wtu4[u4];
    }
    __syncthreads();

    const int w = t >> 6;          // wave id = M-tile
    const int lane = t & 63;
    const int mr = lane & 15, quad = lane >> 4;

    f32x4 acc[9];
    #pragma unroll
    for (int i = 0; i < 9; ++i) acc[i] = (f32x4){0.f, 0.f, 0.f, 0.f};

    #pragma unroll
    for (int kk = 0; kk < 4; ++kk) {
        const bf16x8 a =
            *(const bf16x8*)&sm[(w * 16 + mr) * LDS_STRIDE + kk * 32 + quad * 8];
        #pragma unroll
        for (int tt = 0; tt < 9; ++tt) {
            const bf16x8 b = *(const bf16x8*)&sm[WT_U + (tt * 16 + mr) * LDS_STRIDE +
                                                 kk * 32 + quad * 8];
            acc[tt] = __builtin_amdgcn_mfma_f32_16x16x32_bf16(a, b, acc[tt], 0, 0, 0);
        }
    }

    #pragma unroll
    for (int tt = 0; tt < 8; ++tt) {
        const int col = tt * 16 + mr;
        #pragma unroll
        for (int r = 0; r < 4; ++r) {
            const int node = n0 + w * 16 + quad * 4 + r;
            if (node < NN) hc_bf[(size_t)node * FD + col] = f2bf(acc[tt][r]);
        }
    }
    #pragma unroll
    for (int r = 0; r < 4; ++r) {
        const int node = n0 + w * 16 + quad * 4 + r;
        if (node < NN) {
            if (mr < 4)      A[(size_t)node * NH + mr] = acc[8][r];
            else if (mr < 8) B[(size_t)node * NH + (mr - 4)] = acc[8][r];
        }
    }
}

// ---------------- K3: scan (3 stages) ----------------
__global__ __launch_bounds__(256) void scan1_kernel(const int* __restrict__ deg,
                                                    int* __restrict__ tmp,
                                                    int* __restrict__ bsum) {
    __shared__ int sh[256];
    const int t = threadIdx.x, b = blockIdx.x, i = b * 256 + t;
    const int v = (i < NN) ? deg[i] : 0;
    sh[t] = v;
    __syncthreads();
    #pragma unroll
    for (int off = 1; off < 256; off <<= 1) {
        const int x = (t >= off) ? sh[t - off] : 0;
        __syncthreads();
        sh[t] += x;
        __syncthreads();
    }
    if (i < NN) tmp[i] = sh[t] - v;   // exclusive
    if (t == 255) bsum[b] = sh[t];
}

__global__ __launch_bounds__(512) void scan2_kernel(int* __restrict__ bsum) {
    __shared__ int sh[512];
    const int t = threadIdx.x;
    const int v = (t < NB_SCAN) ? bsum[t] : 0;
    sh[t] = v;
    __syncthreads();
    #pragma unroll
    for (int off = 1; off < 512; off <<= 1) {
        const int x = (t >= off) ? sh[t - off] : 0;
        __syncthreads();
        sh[t] += x;
        __syncthreads();
    }
    if (t < NB_SCAN) bsum[t] = sh[t] - v;   // exclusive
}

__global__ __launch_bounds__(256) void scan3_kernel(const int* __restrict__ tmp,
                                                    const int* __restrict__ bsum,
                                                    int* __restrict__ row_ptr,
                                                    int* __restrict__ cursor) {
    const int i = blockIdx.x * 256 + threadIdx.x;
    if (i < NN) {
        const int v = tmp[i] + bsum[blockIdx.x];
        row_ptr[i] = v;
        cursor[i] = v;
    }
    if (i == 0) row_ptr[NN] = NE;
}

// ---------------- K4: scatter edges into CSR (XCD-sharded, int4) ----------
__global__ __launch_bounds__(256) void scatter_kernel(
    const int* __restrict__ src, const int* __restrict__ dst,
    int* __restrict__ cursor, int* __restrict__ col)
{
    const int shard = blockIdx.x & (NSHARD - 1);
    const int i4 = (blockIdx.x >> 3) * 256 + threadIdx.x;
    if (i4 >= NE4) return;
    const int4 d4 = ((const int4*)dst)[i4];
    const int4 s4 = ((const int4*)src)[i4];
    const int lo = shard * SHARD, hi = lo + SHARD;
    if (d4.x >= lo && d4.x < hi) col[atomicAdd(&cursor[d4.x], 1)] = s4.x;
    if (d4.y >= lo && d4.y < hi) col[atomicAdd(&cursor[d4.y], 1)] = s4.y;
    if (d4.z >= lo && d4.z < hi) col[atomicAdd(&cursor[d4.z], 1)] = s4.z;
    if (d4.w >= lo && d4.w < hi) col[atomicAdd(&cursor[d4.w], 1)] = s4.w;
}

// ---------------- K5: per-node fused softmax + aggregate ----------------
// One 64-lane wave per node, split into two 32-lane halves.
// Lane l: half = l>>5, il = l&31; owns channels [4*il, 4*il+4) (uint2 of hc
// row), head hme = il>>3.
// NEW: the wave register-caches up to 64 edge indices with ONE coalesced
// col load (lane l holds col[p+l]); indices are distributed via __shfl
// (ds_bpermute, ~40cy) instead of per-step memory round-trips. Steps are
// 16 edges wide (8 per half, 8 independent uint2 gathers in flight per
// lane). Invalid edges (beyond deg) are masked with w=0 — their gathers
// read node 0's row (L1-hot broadcast), so no tail special-casing needed.
// Exp dedup: within a half, the lane with il&7 == j computes w for the
// half's edge j; broadcast via __shfl from gbase|j (same half+subgroup).
__global__ __launch_bounds__(256) void agg_kernel(
    const int* __restrict__ row_ptr, const int* __restrict__ col,
    const float* __restrict__ A, const float* __restrict__ B,
    const uint2* __restrict__ hc_u2,
    const float* __restrict__ feat, float* __restrict__ out)
{
    const int n = blockIdx.x * 4 + (threadIdx.x >> 6);
    const int l = threadIdx.x & 63;
    const int half = l >> 5, il = l & 31;
    const int hme = il >> 3;
    const int gbase = l & 0x38;        // same-half, same 8-lane subgroup base
    const int r0 = row_ptr[n], r1 = row_ptr[n + 1];
    const float bh = B[(size_t)n * NH + hme];

    float ssum = 0.f;
    float acc0 = 0.f, acc1 = 0.f, acc2 = 0.f, acc3 = 0.f;

    int p = r0;
    while (p < r1) {
        const int cnt = (r1 - p < 64) ? (r1 - p) : 64;   // edges in this chunk
        const int cidx = (l < cnt) ? col[p + l] : 0;     // one coalesced load
        // q steps 0,16,32,48 -> eq/em <= 63, shfl index always in range
        for (int q = 0; q < cnt; q += 16) {
            // my exp edge (8 per half, covered by il&7)
            const int eq = q + 8 * half + (il & 7);
            const int myc = __shfl(cidx, eq);
            float w = 0.f;
            if (eq < cnt) {
                float e = A[(size_t)myc * NH + hme] + bh;
                e = e > 0.f ? e : 0.2f * e;
                w = __expf(e);
            }
            // distribute the 8 indices of my half's edges
            int cm[8];
            #pragma unroll
            for (int m = 0; m < 8; ++m)
                cm[m] = __shfl(cidx, q + 8 * half + m);
            // issue all 8 gathers (independent, in flight together)
            uint2 u[8];
            #pragma unroll
            for (int m = 0; m < 8; ++m)
                u[m] = hc_u2[(size_t)cm[m] * 32 + il];
            // accumulate (wm == 0 for masked edges)
            #pragma unroll
            for (int m = 0; m < 8; ++m) {
                const float wm = __shfl(w, gbase | m);
                ssum += wm;
                acc0 = fmaf(wm, bf_lo(u[m].x), acc0);
                acc1 = fmaf(wm, bf_hi(u[m].x), acc1);
                acc2 = fmaf(wm, bf_lo(u[m].y), acc2);
                acc3 = fmaf(wm, bf_hi(u[m].y), acc3);
            }
        }
        p += cnt;
    }

    // cross-half combine
    ssum += __shfl_xor(ssum, 32);
    acc0 += __shfl_xor(acc0, 32);
    acc1 += __shfl_xor(acc1, 32);
    acc2 += __shfl_xor(acc2, 32);
    acc3 += __shfl_xor(acc3, 32);

    if (half == 0) {
        const float inv = ssum > 0.f ? 1.f / ssum : 0.f;
        const float4 fv = ((const float4*)(feat + (size_t)n * FD))[il];
        float4 ov;
        ov.x = acc0 * inv + fv.x;
        ov.y = acc1 * inv + fv.y;
        ov.z = acc2 * inv + fv.z;
        ov.w = acc3 * inv + fv.w;
        ((float4*)(out + (size_t)n * FD))[il] = ov;
    }
    if (blockIdx.x == 0 && threadIdx.x == 0) out[(size_t)NN * FD] = 0.f;
}

// ---------------- launcher ----------------
extern "C" void kernel_launch(void* const* d_in, const int* in_sizes, int n_in,
                              void* d_out, int out_size, void* d_ws, size_t ws_size,
                              hipStream_t stream) {
    const float* feat         = (const float*)d_in[0];
    const int*   src          = (const int*)d_in[1];
    const int*   dst          = (const int*)d_in[2];
    const float* Wc           = (const float*)d_in[3];
    const float* Wp           = (const float*)d_in[4];
    const float* attn_src     = (const float*)d_in[5];
    const float* attn_dst     = (const float*)d_in[6];
    const float* pos_attn_src = (const float*)d_in[7];
    const float* pos_attn_dst = (const float*)d_in[8];
    const float* att_comb     = (const float*)d_in[9];
    float* out = (float*)d_out;

    // workspace layout (all 16B-aligned)
    char* w = (char*)d_ws;
    unsigned short* hc_bf = (unsigned short*)w;        w += (size_t)NN * FD * 2;  // 25.6 MB
    float* A       = (float*)w;                        w += (size_t)NN * NH * 4;  // 1.6 MB
    float* B       = (float*)w;                        w += (size_t)NN * NH * 4;  // 1.6 MB
    int*   deg     = (int*)w;                          w += (size_t)NN * 4;
    int*   tmp     = (int*)w;                          w += (size_t)NN * 4;
    int*   row_ptr = (int*)w;                          w += (size_t)(NN + 4) * 4;
    int*   cursor  = (int*)w;                          w += (size_t)NN * 4;
    int*   bsum    = (int*)w;                          w += 512 * 4;
    unsigned short* wt = (unsigned short*)w;           w += (size_t)NOUT * FD * 2;
    int*   col     = (int*)w;                          /* NE*4 = 6.4 MB */

    hipMemsetAsync(deg, 0, (size_t)NN * sizeof(int), stream);
    prep_kernel<<<1, 256, 0, stream>>>(Wc, Wp, attn_src, attn_dst,
                                       pos_attn_src, pos_attn_dst, att_comb, wt);
    hist_kernel<<<NSHARD * NB_E4, 256, 0, stream>>>(dst, deg);
    node_mfma_kernel<<<NGB, 256, 0, stream>>>(feat, wt, hc_bf, A, B);
    scan1_kernel<<<NB_SCAN, 256, 0, stream>>>(deg, tmp, bsum);
    scan2_kernel<<<1, 512, 0, stream>>>(bsum);
    scan3_kernel<<<NB_SCAN, 256, 0, stream>>>(tmp, bsum, row_ptr, cursor);
    scatter_kernel<<<NSHARD * NB_E4, 256, 0, stream>>>(src, dst, cursor, col);
    agg_kernel<<<NN / 4, 256, 0, stream>>>(row_ptr, col, A, B,
                                           (const uint2*)hc_bf, feat, out);
}

// Round 2
// 348.562 us; speedup vs baseline: 1.1152x; 1.0730x over previous
//
#include <hip/hip_runtime.h>
#include <hip/hip_bf16.h>

#define NN 100000   // nodes
#define NE 1600000  // edges
#define FD 128      // IN_DIM = H*D
#define CD 112      // CONTENT_DIM
#define PDIM 16     // POS_DIM
#define NH 4        // heads
#define NB_SCAN 391 // ceil(NN/256)
#define NSHARD 8    // dst shards
#define SHARD 12500 // NN / NSHARD
#define NE4 400000  // NE / 4
#define NB_E4 1563  // ceil(NE4 / 256)

#define NOUT 144        // 128 hc cols + 4 A + 4 B + 8 pad
#define MBLK 64         // nodes per block in node GEMM
#define LDS_STRIDE 136  // ushort stride per LDS row
#define WT_U (MBLK * LDS_STRIDE)
#define NGB 1563        // ceil(NN / MBLK)
#define FUSE_GRID (NGB * 9)  // 14067 = 1563 mfma blocks + 12504 hist blocks

using bf16x8 = __attribute__((ext_vector_type(8))) short;
using f32x4  = __attribute__((ext_vector_type(4))) float;

__device__ __forceinline__ unsigned short f2bf(float x) {
    union { float f; unsigned int u; } v; v.f = x;
    return (unsigned short)((v.u + 0x7fffu + ((v.u >> 16) & 1u)) >> 16);  // RNE
}
__device__ __forceinline__ float bf_lo(unsigned int u) { return __uint_as_float(u << 16); }
__device__ __forceinline__ float bf_hi(unsigned int u) { return __uint_as_float(u & 0xffff0000u); }

// ---------------- K0: build combined bf16 weight matrix W'T [144][128] ----
__global__ __launch_bounds__(256) void prep_kernel(
    const float* __restrict__ Wc, const float* __restrict__ Wp,
    const float* __restrict__ attn_src, const float* __restrict__ attn_dst,
    const float* __restrict__ pos_attn_src, const float* __restrict__ pos_attn_dst,
    const float* __restrict__ att_comb, unsigned short* __restrict__ wt)
{
    __shared__ float sA[NH * FD], sB[NH * FD];
    const int t = threadIdx.x;
    #pragma unroll
    for (int r = 0; r < 2; ++r) {
        const int idx = t + r * 256;       // 0..511
        const int h = idx >> 7, k = idx & 127;
        const float c0 = att_comb[h * 2], c1 = att_comb[h * 2 + 1];
        float sa = 0.f, sb = 0.f;
        if (k < CD) {
            #pragma unroll 8
            for (int d = 0; d < 32; ++d) {
                const float wv = Wc[(size_t)(h * 32 + d) * CD + k];
                sa = fmaf(wv, attn_src[h * 32 + d], sa);
                sb = fmaf(wv, attn_dst[h * 32 + d], sb);
            }
            sa *= c0; sb *= c0;
        } else {
            const int k2 = k - CD;
            #pragma unroll
            for (int d4 = 0; d4 < 8; ++d4) {
                const float wv = Wp[(h * 8 + d4) * PDIM + k2];
                sa = fmaf(wv, pos_attn_src[h * 8 + d4], sa);
                sb = fmaf(wv, pos_attn_dst[h * 8 + d4], sb);
            }
            sa *= c1; sb *= c1;
        }
        sA[idx] = sa; sB[idx] = sb;
    }
    __syncthreads();
    #pragma unroll
    for (int it = 0; it < 72; ++it) {
        const int e = t + it * 256;        // < 18432 = 144*128
        const int row = e >> 7, k = e & 127;
        float val;
        if (row < 128)      val = (k < CD) ? Wc[(size_t)row * CD + k] : 0.f;
        else if (row < 132) val = sA[(row - 128) * FD + k];
        else if (row < 136) val = sB[(row - 132) * FD + k];
        else                val = 0.f;
        wt[e] = f2bf(val);
    }
}

// ---------------- K1: FUSED node-MFMA ∥ degree histogram -------------------
// Grid = NGB*9. Every 9th block (bid%9==0) is an MFMA tile (id bid/9);
// the other 8 per group are hist blocks (id g*8 + r-1, bijective onto
// [0, NSHARD*NB_E4)). The two populations are independent (different
// inputs/outputs) and co-execute: hist is memory/atomic-latency work,
// mfma is LDS/MFMA work. Hist atomics are no-return (fire-and-forget),
// so the 56KB-LDS 2-blocks/CU cap does not starve them.
__global__ __launch_bounds__(256) void mfma_hist_kernel(
    const float* __restrict__ feat, const unsigned short* __restrict__ wt,
    unsigned short* __restrict__ hc_bf, float* __restrict__ A,
    float* __restrict__ B, const int* __restrict__ dst, int* __restrict__ deg)
{
    __shared__ __align__(16) unsigned short sm[WT_U + NOUT * LDS_STRIDE];  // 56,576 B
    const int bid = blockIdx.x;
    const int g = bid / 9, r9 = bid % 9;
    const int t = threadIdx.x;

    if (r9 != 0) {
        // ---- hist part ----
        const int histid = g * 8 + (r9 - 1);        // 0..12503
        const int shard = histid & (NSHARD - 1);
        const int i4 = (histid >> 3) * 256 + t;
        if (i4 >= NE4) return;
        const int4 d4 = ((const int4*)dst)[i4];
        const int lo = shard * SHARD, hi = lo + SHARD;
        if (d4.x >= lo && d4.x < hi) atomicAdd(&deg[d4.x], 1);
        if (d4.y >= lo && d4.y < hi) atomicAdd(&deg[d4.y], 1);
        if (d4.z >= lo && d4.z < hi) atomicAdd(&deg[d4.z], 1);
        if (d4.w >= lo && d4.w < hi) atomicAdd(&deg[d4.w], 1);
        return;
    }

    // ---- mfma part ----
    unsigned int* smu = (unsigned int*)sm;
    const int n0 = g * MBLK;

    // feat staging: 64 rows x 128 f32 = 2048 float4, 8 iters
    #pragma unroll
    for (int it = 0; it < 8; ++it) {
        const int e4 = t + it * 256;           // float4 index < 2048
        const int row = e4 >> 5, c4 = e4 & 31;
        uint2 packed = make_uint2(0u, 0u);
        if (n0 + row < NN) {
            const float4 gv = ((const float4*)(feat + (size_t)n0 * FD))[e4];
            packed.x = (unsigned int)f2bf(gv.x) | ((unsigned int)f2bf(gv.y) << 16);
            packed.y = (unsigned int)f2bf(gv.z) | ((unsigned int)f2bf(gv.w) << 16);
        }
        *(uint2*)&smu[row * (LDS_STRIDE / 2) + c4 * 2] = packed;
    }
    // wt staging: 144 rows x 64 u32 = 2304 uint4, 9 iters
    const uint4* wtu4 = (const uint4*)wt;
    #pragma unroll
    for (int it = 0; it < 9; ++it) {
        const int u4 = t + it * 256;           // uint4 index < 2304
        const int row = u4 >> 4, c16 = u4 & 15;
        *(uint4*)&smu[WT_U / 2 + row * (LDS_STRIDE / 2) + c16 * 4] = wtu4[u4];
    }
    __syncthreads();

    const int w = t >> 6;          // wave id = M-tile
    const int lane = t & 63;
    const int mr = lane & 15, quad = lane >> 4;

    f32x4 acc[9];
    #pragma unroll
    for (int i = 0; i < 9; ++i) acc[i] = (f32x4){0.f, 0.f, 0.f, 0.f};

    #pragma unroll
    for (int kk = 0; kk < 4; ++kk) {
        const bf16x8 a =
            *(const bf16x8*)&sm[(w * 16 + mr) * LDS_STRIDE + kk * 32 + quad * 8];
        #pragma unroll
        for (int tt = 0; tt < 9; ++tt) {
            const bf16x8 b = *(const bf16x8*)&sm[WT_U + (tt * 16 + mr) * LDS_STRIDE +
                                                 kk * 32 + quad * 8];
            acc[tt] = __builtin_amdgcn_mfma_f32_16x16x32_bf16(a, b, acc[tt], 0, 0, 0);
        }
    }

    #pragma unroll
    for (int tt = 0; tt < 8; ++tt) {
        const int col = tt * 16 + mr;
        #pragma unroll
        for (int rr = 0; rr < 4; ++rr) {
            const int node = n0 + w * 16 + quad * 4 + rr;
            if (node < NN) hc_bf[(size_t)node * FD + col] = f2bf(acc[tt][rr]);
        }
    }
    #pragma unroll
    for (int rr = 0; rr < 4; ++rr) {
        const int node = n0 + w * 16 + quad * 4 + rr;
        if (node < NN) {
            if (mr < 4)      A[(size_t)node * NH + mr] = acc[8][rr];
            else if (mr < 8) B[(size_t)node * NH + (mr - 4)] = acc[8][rr];
        }
    }
}

// ---------------- K3: scan (3 stages) ----------------
__global__ __launch_bounds__(256) void scan1_kernel(const int* __restrict__ deg,
                                                    int* __restrict__ tmp,
                                                    int* __restrict__ bsum) {
    __shared__ int sh[256];
    const int t = threadIdx.x, b = blockIdx.x, i = b * 256 + t;
    const int v = (i < NN) ? deg[i] : 0;
    sh[t] = v;
    __syncthreads();
    #pragma unroll
    for (int off = 1; off < 256; off <<= 1) {
        const int x = (t >= off) ? sh[t - off] : 0;
        __syncthreads();
        sh[t] += x;
        __syncthreads();
    }
    if (i < NN) tmp[i] = sh[t] - v;   // exclusive
    if (t == 255) bsum[b] = sh[t];
}

__global__ __launch_bounds__(512) void scan2_kernel(int* __restrict__ bsum) {
    __shared__ int sh[512];
    const int t = threadIdx.x;
    const int v = (t < NB_SCAN) ? bsum[t] : 0;
    sh[t] = v;
    __syncthreads();
    #pragma unroll
    for (int off = 1; off < 512; off <<= 1) {
        const int x = (t >= off) ? sh[t - off] : 0;
        __syncthreads();
        sh[t] += x;
        __syncthreads();
    }
    if (t < NB_SCAN) bsum[t] = sh[t] - v;   // exclusive
}

__global__ __launch_bounds__(256) void scan3_kernel(const int* __restrict__ tmp,
                                                    const int* __restrict__ bsum,
                                                    int* __restrict__ row_ptr,
                                                    int* __restrict__ cursor) {
    const int i = blockIdx.x * 256 + threadIdx.x;
    if (i < NN) {
        const int v = tmp[i] + bsum[blockIdx.x];
        row_ptr[i] = v;
        cursor[i] = v;
    }
    if (i == 0) row_ptr[NN] = NE;
}

// ---------------- K4: scatter edges into CSR (sharded, int4) ----------
__global__ __launch_bounds__(256) void scatter_kernel(
    const int* __restrict__ src, const int* __restrict__ dst,
    int* __restrict__ cursor, int* __restrict__ col)
{
    const int shard = blockIdx.x & (NSHARD - 1);
    const int i4 = (blockIdx.x >> 3) * 256 + threadIdx.x;
    if (i4 >= NE4) return;
    const int4 d4 = ((const int4*)dst)[i4];
    const int4 s4 = ((const int4*)src)[i4];
    const int lo = shard * SHARD, hi = lo + SHARD;
    if (d4.x >= lo && d4.x < hi) col[atomicAdd(&cursor[d4.x], 1)] = s4.x;
    if (d4.y >= lo && d4.y < hi) col[atomicAdd(&cursor[d4.y], 1)] = s4.y;
    if (d4.z >= lo && d4.z < hi) col[atomicAdd(&cursor[d4.z], 1)] = s4.z;
    if (d4.w >= lo && d4.w < hi) col[atomicAdd(&cursor[d4.w], 1)] = s4.w;
}

// ---------------- K5: per-node fused softmax + aggregate ----------------
// NEW: one node per 32-lane HALF (2 nodes/wave, 8 nodes/block). Each half
// owns all 128 channels (32 lanes x uint2), so halves are fully independent:
// 2 latency chains per wave, no cross-half reduction. Steps are 16 edges
// wide per half (16 independent uint2 gathers in flight per lane).
// Lane: il = tid&31 (channel group), hme = il>>3 (head), hbase = half's
// wave-lane base, gbase = same-half same-head subgroup base. All shfl
// sources stay within the requesting half; loop control is half-uniform.
// Exp dedup: lane j = il&7 computes w for half-edges q+j (w0) and q+8+j
// (w1); broadcast via shfl. Masked edges (>= cnt) get w=0 and gather node
// 0's row (L1-hot), so no tail path.
__global__ __launch_bounds__(256) void agg_kernel(
    const int* __restrict__ row_ptr, const int* __restrict__ col,
    const float* __restrict__ A, const float* __restrict__ B,
    const uint2* __restrict__ hc_u2,
    const float* __restrict__ feat, float* __restrict__ out)
{
    const int n = blockIdx.x * 8 + (threadIdx.x >> 5);   // node per half
    const int il = threadIdx.x & 31;
    const int hme = il >> 3;
    const int hbase = threadIdx.x & 0x20;      // 0 or 32
    const int gbase = hbase | (il & 0x18);     // same half, same head subgroup
    const int r0 = row_ptr[n], r1 = row_ptr[n + 1];
    const float bh = B[(size_t)n * NH + hme];

    float ssum = 0.f;
    float acc0 = 0.f, acc1 = 0.f, acc2 = 0.f, acc3 = 0.f;

    int p = r0;
    while (p < r1) {
        const int cnt = (r1 - p < 32) ? (r1 - p) : 32;   // edges this chunk
        const int cidx = (il < cnt) ? col[p + il] : 0;   // coalesced per half
        for (int q = 0; q < cnt; q += 16) {
            const int j = il & 7;
            // my two exp edges: q+j and q+8+j (same head subgroup covers all)
            const int myc0 = __shfl(cidx, hbase | (q + j));
            const int myc1 = __shfl(cidx, hbase | (q + 8 + j));
            float w0 = 0.f, w1 = 0.f;
            if (q + j < cnt) {
                float e = A[(size_t)myc0 * NH + hme] + bh;
                e = e > 0.f ? e : 0.2f * e;
                w0 = __expf(e);
            }
            if (q + 8 + j < cnt) {
                float e = A[(size_t)myc1 * NH + hme] + bh;
                e = e > 0.f ? e : 0.2f * e;
                w1 = __expf(e);
            }
            // distribute 16 edge indices of my half
            int cm[16];
            #pragma unroll
            for (int m = 0; m < 16; ++m)
                cm[m] = __shfl(cidx, hbase | (q + m));
            // 16 independent gathers in flight
            uint2 u[16];
            #pragma unroll
            for (int m = 0; m < 16; ++m)
                u[m] = hc_u2[(size_t)cm[m] * 32 + il];
            #pragma unroll
            for (int m = 0; m < 16; ++m) {
                const float wm = (m < 8) ? __shfl(w0, gbase | m)
                                         : __shfl(w1, gbase | (m - 8));
                ssum += wm;
                acc0 = fmaf(wm, bf_lo(u[m].x), acc0);
                acc1 = fmaf(wm, bf_hi(u[m].x), acc1);
                acc2 = fmaf(wm, bf_lo(u[m].y), acc2);
                acc3 = fmaf(wm, bf_hi(u[m].y), acc3);
            }
        }
        p += cnt;
    }

    // ssum is replicated across the half's lanes (every lane added all wm)
    const float inv = ssum > 0.f ? 1.f / ssum : 0.f;
    const float4 fv = ((const float4*)(feat + (size_t)n * FD))[il];
    float4 ov;
    ov.x = acc0 * inv + fv.x;
    ov.y = acc1 * inv + fv.y;
    ov.z = acc2 * inv + fv.z;
    ov.w = acc3 * inv + fv.w;
    ((float4*)(out + (size_t)n * FD))[il] = ov;

    if (blockIdx.x == 0 && threadIdx.x == 0) out[(size_t)NN * FD] = 0.f;
}

// ---------------- launcher ----------------
extern "C" void kernel_launch(void* const* d_in, const int* in_sizes, int n_in,
                              void* d_out, int out_size, void* d_ws, size_t ws_size,
                              hipStream_t stream) {
    const float* feat         = (const float*)d_in[0];
    const int*   src          = (const int*)d_in[1];
    const int*   dst          = (const int*)d_in[2];
    const float* Wc           = (const float*)d_in[3];
    const float* Wp           = (const float*)d_in[4];
    const float* attn_src     = (const float*)d_in[5];
    const float* attn_dst     = (const float*)d_in[6];
    const float* pos_attn_src = (const float*)d_in[7];
    const float* pos_attn_dst = (const float*)d_in[8];
    const float* att_comb     = (const float*)d_in[9];
    float* out = (float*)d_out;

    // workspace layout (all 16B-aligned)
    char* w = (char*)d_ws;
    unsigned short* hc_bf = (unsigned short*)w;        w += (size_t)NN * FD * 2;  // 25.6 MB
    float* A       = (float*)w;                        w += (size_t)NN * NH * 4;  // 1.6 MB
    float* B       = (float*)w;                        w += (size_t)NN * NH * 4;  // 1.6 MB
    int*   deg     = (int*)w;                          w += (size_t)NN * 4;
    int*   tmp     = (int*)w;                          w += (size_t)NN * 4;
    int*   row_ptr = (int*)w;                          w += (size_t)(NN + 4) * 4;
    int*   cursor  = (int*)w;                          w += (size_t)NN * 4;
    int*   bsum    = (int*)w;                          w += 512 * 4;
    unsigned short* wt = (unsigned short*)w;           w += (size_t)NOUT * FD * 2;
    int*   col     = (int*)w;                          /* NE*4 = 6.4 MB */

    hipMemsetAsync(deg, 0, (size_t)NN * sizeof(int), stream);
    prep_kernel<<<1, 256, 0, stream>>>(Wc, Wp, attn_src, attn_dst,
                                       pos_attn_src, pos_attn_dst, att_comb, wt);
    mfma_hist_kernel<<<FUSE_GRID, 256, 0, stream>>>(feat, wt, hc_bf, A, B, dst, deg);
    scan1_kernel<<<NB_SCAN, 256, 0, stream>>>(deg, tmp, bsum);
    scan2_kernel<<<1, 512, 0, stream>>>(bsum);
    scan3_kernel<<<NB_SCAN, 256, 0, stream>>>(tmp, bsum, row_ptr, cursor);
    scatter_kernel<<<NSHARD * NB_E4, 256, 0, stream>>>(src, dst, cursor, col);
    agg_kernel<<<NN / 8, 256, 0, stream>>>(row_ptr, col, A, B,
                                           (const uint2*)hc_bf, feat, out);
}